// Round 2
// baseline (51.579 us; speedup 1.0000x reference)
//
#include <hip/hip_runtime.h>

#define D_MODEL   256
#define NUM_TYPES 7
#define BATCH     2
#define NLANES    512

typedef __bf16 bf16x8 __attribute__((ext_vector_type(8)));
typedef float  floatx4 __attribute__((ext_vector_type(4)));

// ---------------- Kernel 1: H = [x@W1a + b1 | x@W1b] ----------------
// H is (1024 x 512) fp32 in workspace. Cols 0..255 = hi (+b1), 256..511 = hj.
#define K1_ROWS 16
#define K1_COLS 128

__global__ __launch_bounds__(256) void k_h_gemm(
    const float* __restrict__ x, const float* __restrict__ W1,
    const float* __restrict__ b1, float* __restrict__ H)
{
    __shared__ float xs[K1_ROWS][D_MODEL];   // 16 KB
    const int tid = threadIdx.x;
    const int c0  = blockIdx.x * K1_COLS;
    const int r0  = blockIdx.y * K1_ROWS;

    // stage 16 rows of x (16*256 floats = 1024 float4)
    {
        const float4* src = (const float4*)(x + (size_t)r0 * D_MODEL);
        float4* dst = (float4*)(&xs[0][0]);
        #pragma unroll
        for (int q = 0; q < 4; ++q)
            dst[tid + q * 256] = src[tid + q * 256];
    }
    __syncthreads();

    const int c  = c0 + (tid & (K1_COLS - 1));  // global output col 0..511
    const int rg = tid >> 7;                     // 0..1 (8 rows each)

    // W element (k, c): c<256 -> W1[k][c] ; c>=256 -> W1[256+k][c-256]
    const float* Wb = (c < D_MODEL)
        ? (W1 + c)
        : (W1 + (size_t)D_MODEL * D_MODEL + (c - D_MODEL));

    float acc[8];
    #pragma unroll
    for (int rr = 0; rr < 8; ++rr) acc[rr] = 0.f;

    #pragma unroll 4
    for (int k = 0; k < D_MODEL; ++k) {
        const float w = Wb[(size_t)k * D_MODEL];
        #pragma unroll
        for (int rr = 0; rr < 8; ++rr)
            acc[rr] = fmaf(xs[rg * 8 + rr][k], w, acc[rr]);
    }

    const float bias = (c < D_MODEL) ? b1[c] : 0.f;
    #pragma unroll
    for (int rr = 0; rr < 8; ++rr)
        H[(size_t)(r0 + rg * 8 + rr) * 512 + c] = acc[rr] + bias;
}

// ---------------- Kernel 2 (MFMA): out[b,i,j,:] = relu(Hi[i]+Hj[j]) @ W2 + b2 ----------
// Per wave: one 16-wide j-group, 8 i values. D = A*B with
//   A = W2^T chunk (rows = 16 types (7 real), cols = k)   -> held in VGPRs
//   B = act chunk  (rows = k, cols = 16 j)                -> built on the fly
// mfma_f32_16x16x32_bf16 lane layout:
//   A[row][k]: row = lane&15, k = (lane>>4)*8 + e
//   B[k][col]: col = lane&15, k = (lane>>4)*8 + e
//   D[row][col]: col = lane&15, row = (lane>>4)*4 + r     (m89-verified)
#define LDH 260   // padded LDS stride (floats); 260%32=4 -> bank-balanced b128 reads

__global__ __launch_bounds__(256) void k_pair_mfma(
    const float* __restrict__ H, const float* __restrict__ W2,
    const float* __restrict__ b2, float* __restrict__ out)
{
    __shared__ float hjs[16][LDH];   // 16.25 KB

    const int tid  = threadIdx.x;
    const int lane = tid & 63;
    const int w    = tid >> 6;                 // wave 0..3
    const int b    = blockIdx.z;
    const int j0   = blockIdx.x * 16;
    const int i0   = blockIdx.y * 32 + w * 8;  // 8 i's per wave

    // ---- stage Hj rows j0..j0+15 (cols 256..511 of H), 1024 float4 ----
    #pragma unroll
    for (int q = 0; q < 4; ++q) {
        const int f  = tid + q * 256;          // 0..1023
        const int r  = f >> 6;                 // row 0..15
        const int kk = (f & 63) << 2;          // float offset 0..252
        const float4 v = *(const float4*)(
            H + (size_t)(b * NLANES + j0 + r) * 512 + D_MODEL + kk);
        *(float4*)&hjs[r][kk] = v;
    }

    // ---- A operand: W2^T fragments, resident for whole kernel (32 VGPRs) ----
    const int t  = lane & 15;                  // type row
    const int ks = (lane >> 4) * 8;            // k sub-slice base
    bf16x8 w2f[8];
    #pragma unroll
    for (int kc = 0; kc < 8; ++kc) {
        #pragma unroll
        for (int e = 0; e < 8; ++e) {
            const float v = (t < NUM_TYPES)
                ? W2[(size_t)(kc * 32 + ks + e) * NUM_TYPES + t] : 0.f;
            w2f[kc][e] = (__bf16)v;
        }
    }

    // ---- bias per D row-group ----
    const int tb = (lane >> 4) * 4;            // D row base (= type) for this lane
    float bias[4];
    #pragma unroll
    for (int r = 0; r < 4; ++r)
        bias[r] = (tb + r < NUM_TYPES) ? b2[tb + r] : 0.f;

    __syncthreads();

    const int jr = lane & 15;                  // j row in LDS tile / D col
    const float* Hi_base = H + (size_t)b * NLANES * 512;

    #pragma unroll 2
    for (int ii = 0; ii < 8; ++ii) {
        const int i = i0 + ii;
        const float* hi = Hi_base + (size_t)i * 512 + ks;
        floatx4 acc = {0.f, 0.f, 0.f, 0.f};

        #pragma unroll
        for (int kc = 0; kc < 8; ++kc) {
            // Hi slice: uniform across each 16-lane group (broadcast-friendly)
            const float4 q0 = *(const float4*)(hi + kc * 32);
            const float4 q1 = *(const float4*)(hi + kc * 32 + 4);
            // Hj slice: lane's own j row
            const float* hj = &hjs[jr][kc * 32 + ks];
            const float4 p0 = *(const float4*)(hj);
            const float4 p1 = *(const float4*)(hj + 4);

            bf16x8 bf;
            #pragma unroll
            for (int e = 0; e < 4; ++e) {
                const float a0 = fmaxf(((const float*)&q0)[e] + ((const float*)&p0)[e], 0.f);
                const float a1 = fmaxf(((const float*)&q1)[e] + ((const float*)&p1)[e], 0.f);
                bf[e]     = (__bf16)a0;
                bf[e + 4] = (__bf16)a1;
            }
            acc = __builtin_amdgcn_mfma_f32_16x16x32_bf16(w2f[kc], bf, acc, 0, 0, 0);
        }

        // ---- store: lane holds D[tb..tb+3][jr]; only t<7 are real ----
        if (lane < 32) {
            float* op = out + ((size_t)(b * NLANES + i) * NLANES + (j0 + jr)) * NUM_TYPES + tb;
            if (tb == 0) {
                float v4[4] = { acc[0] + bias[0], acc[1] + bias[1],
                                acc[2] + bias[2], acc[3] + bias[3] };
                __builtin_memcpy(op, v4, 16);
            } else {
                float v2[2] = { acc[0] + bias[0], acc[1] + bias[1] };
                __builtin_memcpy(op, v2, 8);
                op[2] = acc[2] + bias[2];
            }
        }
    }
}

extern "C" void kernel_launch(void* const* d_in, const int* in_sizes, int n_in,
                              void* d_out, int out_size, void* d_ws, size_t ws_size,
                              hipStream_t stream) {
    const float* x  = (const float*)d_in[0];   // (2,512,256)
    const float* W1 = (const float*)d_in[1];   // (512,256)
    const float* b1 = (const float*)d_in[2];   // (256)
    const float* W2 = (const float*)d_in[3];   // (256,7)
    const float* b2 = (const float*)d_in[4];   // (7)
    float* out = (float*)d_out;                // (2,512,512,7) fp32
    float* H   = (float*)d_ws;                 // 1024*512 floats = 2 MB

    // Kernel 1: 512 cols / 128 = 4 col-tiles, 1024 rows / 16 = 64 row-tiles
    k_h_gemm<<<dim3(4, 64), 256, 0, stream>>>(x, W1, b1, H);

    // Kernel 2: (j-groups of 16, i-tiles of 32, batch)
    k_pair_mfma<<<dim3(NLANES / 16, NLANES / 32, BATCH), 256, 0, stream>>>(H, W2, b2, out);
}